// Round 1
// baseline (88.226 us; speedup 1.0000x reference)
//
#include <hip/hip_runtime.h>
#include <math.h>

#define LAMBDA_DECAY 0.01f
#define ALPHA 0.95f
#define LN_EPS 1e-5f

static __device__ __forceinline__ float wave_sum(float v) {
#pragma unroll
    for (int o = 32; o > 0; o >>= 1) v += __shfl_down(v, o);
    return v;
}
static __device__ __forceinline__ float wave_max(float v) {
#pragma unroll
    for (int o = 32; o > 0; o >>= 1) v = fmaxf(v, __shfl_down(v, o));
    return v;
}

// Block-wide sum broadcast to all threads. sh must hold >= NW floats.
template <int NW>
static __device__ float block_sum(float v, float* sh) {
    int lane = threadIdx.x & 63;
    int w = threadIdx.x >> 6;
    v = wave_sum(v);
    if (lane == 0) sh[w] = v;
    __syncthreads();
    if (threadIdx.x < 64) {
        float x = (threadIdx.x < NW) ? sh[threadIdx.x] : 0.0f;
        x = wave_sum(x);
        if (threadIdx.x == 0) sh[0] = x;
    }
    __syncthreads();
    float r = sh[0];
    __syncthreads();
    return r;
}

template <int NW>
static __device__ float block_max(float v, float* sh) {
    int lane = threadIdx.x & 63;
    int w = threadIdx.x >> 6;
    v = wave_max(v);
    if (lane == 0) sh[w] = v;
    __syncthreads();
    if (threadIdx.x < 64) {
        float x = (threadIdx.x < NW) ? sh[threadIdx.x] : -3.4e38f;
        x = wave_max(x);
        if (threadIdx.x == 0) sh[0] = x;
    }
    __syncthreads();
    float r = sh[0];
    __syncthreads();
    return r;
}

// Kernel 1: scores[i] = dot(states[i], current) * scale. One wave per row.
__global__ __launch_bounds__(256) void scores_kernel(
    const float* __restrict__ states, const float* __restrict__ cur,
    float* __restrict__ scores, int M, int D, float scale)
{
    int gwave = (int)((blockIdx.x * 256u + threadIdx.x) >> 6);
    int lane = threadIdx.x & 63;
    if (gwave >= M) return;
    const float4* row = (const float4*)(states + (size_t)gwave * D);
    const float4* c4 = (const float4*)cur;
    int n4 = D >> 2;
    float sum = 0.0f;
    for (int k = lane; k < n4; k += 64) {
        float4 a = row[k];
        float4 b = c4[k];
        sum = fmaf(a.x, b.x, sum);
        sum = fmaf(a.y, b.y, sum);
        sum = fmaf(a.z, b.z, sum);
        sum = fmaf(a.w, b.w, sum);
    }
    sum = wave_sum(sum);
    if (lane == 0) scores[gwave] = sum * scale;
}

// Kernel 2: single block. Softmax + decayed-weight renormalization folded into
// one coefficient per row:  c_i = e_i * w_i / (S_ew + 1e-9 * E)
// where e_i = exp(s_i - max), E = sum e, S_ew = sum e*w,
// w_i = weights[i] * exp(-lambda*|t_new - ts_i|).
// (attn=e/E; wa=attn*w; wa/(sum(wa)+1e-9) == e*w/(S_ew + 1e-9*E))
// Also zero-initializes the accumulator region.
__global__ __launch_bounds__(1024) void coef_kernel(
    const float* __restrict__ scores, const float* __restrict__ weights,
    const float* __restrict__ ts, const float* __restrict__ t_new,
    float* __restrict__ coef, float* __restrict__ acc, int M, int D)
{
    __shared__ float sh[16];
    int tid = threadIdx.x;

    float m = -3.4e38f;
    for (int i = tid; i < M; i += 1024) m = fmaxf(m, scores[i]);
    m = block_max<16>(m, sh);

    float tn = t_new[0];
    float E = 0.0f, S = 0.0f;
    for (int i = tid; i < M; i += 1024) {
        float e = expf(scores[i] - m);
        float w = weights[i] * expf(-LAMBDA_DECAY * fabsf(tn - ts[i]));
        E += e;
        S += e * w;
    }
    E = block_sum<16>(E, sh);
    S = block_sum<16>(S, sh);

    float inv = 1.0f / (S + 1e-9f * E);
    for (int i = tid; i < M; i += 1024) {
        float e = expf(scores[i] - m);
        float w = weights[i] * expf(-LAMBDA_DECAY * fabsf(tn - ts[i]));
        coef[i] = e * w * inv;
    }

    for (int d = tid; d < D; d += 1024) acc[d] = 0.0f;
}

// Kernel 3: acc[d] += sum_{r in chunk} coef[r] * states[r][d].
// grid = (D/1024, M/rowsPerBlock), block = 256, float4 per thread.
__global__ __launch_bounds__(256) void wsum_kernel(
    const float* __restrict__ states, const float* __restrict__ coef,
    float* __restrict__ acc, int M, int D, int rowsPerBlock)
{
    int c = blockIdx.x * (256 * 4) + threadIdx.x * 4;
    if (c + 3 >= D + 4) return;  // D divisible by 1024 in practice
    int r0 = blockIdx.y * rowsPerBlock;
    int r1 = r0 + rowsPerBlock;
    if (r1 > M) r1 = M;
    float4 a = make_float4(0.0f, 0.0f, 0.0f, 0.0f);
    for (int r = r0; r < r1; ++r) {
        float cf = coef[r];
        const float4 s = *(const float4*)(states + (size_t)r * D + c);
        a.x = fmaf(cf, s.x, a.x);
        a.y = fmaf(cf, s.y, a.y);
        a.z = fmaf(cf, s.z, a.z);
        a.w = fmaf(cf, s.w, a.w);
    }
    atomicAdd(&acc[c + 0], a.x);
    atomicAdd(&acc[c + 1], a.y);
    atomicAdd(&acc[c + 2], a.z);
    atomicAdd(&acc[c + 3], a.w);
}

// Kernel 4: new = alpha*cur + (1-alpha)*acc; out = layernorm(new). Single block.
__global__ __launch_bounds__(1024) void finalize_kernel(
    const float* __restrict__ cur, const float* __restrict__ acc,
    float* __restrict__ out, int D)
{
    __shared__ float sh[16];
    int tid = threadIdx.x;
    float s = 0.0f, s2 = 0.0f;
    for (int d = tid; d < D; d += 1024) {
        float v = ALPHA * cur[d] + (1.0f - ALPHA) * acc[d];
        s += v;
        s2 += v * v;
    }
    s = block_sum<16>(s, sh);
    s2 = block_sum<16>(s2, sh);
    float mean = s / (float)D;
    float var = s2 / (float)D - mean * mean;
    float inv = 1.0f / sqrtf(var + LN_EPS);
    for (int d = tid; d < D; d += 1024) {
        float v = ALPHA * cur[d] + (1.0f - ALPHA) * acc[d];
        out[d] = (v - mean) * inv;
    }
}

extern "C" void kernel_launch(void* const* d_in, const int* in_sizes, int n_in,
                              void* d_out, int out_size, void* d_ws, size_t ws_size,
                              hipStream_t stream) {
    const float* states       = (const float*)d_in[0];
    const float* weights      = (const float*)d_in[1];
    const float* timestamps   = (const float*)d_in[2];
    const float* current      = (const float*)d_in[3];
    // d_in[4] = sensed_state: not used in the output math.
    const float* t_new        = (const float*)d_in[5];
    float* out = (float*)d_out;

    const int M = in_sizes[1];               // 8192
    const int D = in_sizes[3];               // 4096

    float* ws     = (float*)d_ws;
    float* scores = ws;                      // [M]
    float* coef   = ws + M;                  // [M]
    float* acc    = ws + 2 * (size_t)M;      // [D]

    const float scale = 1.0f / sqrtf((float)D);

    // K1: scores (one wave/row, 4 rows per 256-thread block)
    {
        int waves = M;
        int blocks = (waves * 64 + 255) / 256;
        scores_kernel<<<blocks, 256, 0, stream>>>(states, current, scores, M, D, scale);
    }
    // K2: softmax+weight coefficients, zero acc
    coef_kernel<<<1, 1024, 0, stream>>>(scores, weights, timestamps, t_new, coef, acc, M, D);
    // K3: weighted column sum
    {
        const int rowsPerBlock = 128;
        dim3 grid(D / 1024, (M + rowsPerBlock - 1) / rowsPerBlock);
        wsum_kernel<<<grid, 256, 0, stream>>>(states, coef, acc, M, D, rowsPerBlock);
    }
    // K4: blend + layernorm
    finalize_kernel<<<1, 1024, 0, stream>>>(current, acc, out, D);
}

// Round 2
// 69.382 us; speedup vs baseline: 1.2716x; 1.2716x over previous
//
#include <hip/hip_runtime.h>
#include <math.h>

#define LAMBDA_DECAY 0.01f
#define ALPHA 0.95f
#define LN_EPS 1e-5f

static __device__ __forceinline__ float wave_sum(float v) {
#pragma unroll
    for (int o = 32; o > 0; o >>= 1) v += __shfl_down(v, o);
    return v;
}

// Block-wide sum broadcast to all threads. sh must hold >= NW floats.
template <int NW, int BS>
static __device__ float block_sum(float v, float* sh) {
    int lane = threadIdx.x & 63;
    int w = threadIdx.x >> 6;
    v = wave_sum(v);
    if (lane == 0) sh[w] = v;
    __syncthreads();
    if (threadIdx.x < 64) {
        float x = (threadIdx.x < NW) ? sh[threadIdx.x] : 0.0f;
        x = wave_sum(x);
        if (threadIdx.x == 0) sh[0] = x;
    }
    __syncthreads();
    float r = sh[0];
    __syncthreads();
    return r;
}

// K1: one wave per row.
//   score_i = dot(states[i], cur) * scale
//   w_i     = weights[i] * exp(-lambda*|t_new - ts_i|)
//   p_i     = exp(score_i) * w_i                  (no max subtraction: it
//             cancels exactly in c_i = e_i w_i / (S + 1e-9 E); scores ~N(0,1))
// Per-block partial sums of E = sum exp(score), S = sum p go to partE/partS.
__global__ __launch_bounds__(256) void scores_kernel(
    const float* __restrict__ states, const float* __restrict__ cur,
    const float* __restrict__ weights, const float* __restrict__ ts,
    const float* __restrict__ t_new,
    float* __restrict__ p, float* __restrict__ partE, float* __restrict__ partS,
    int M, int D, float scale)
{
    __shared__ float shE[4], shS[4];
    int wid = threadIdx.x >> 6;
    int lane = threadIdx.x & 63;
    int row = blockIdx.x * 4 + wid;

    float e = 0.0f, pw = 0.0f;
    if (row < M) {
        const float4* rp = (const float4*)(states + (size_t)row * D);
        const float4* c4 = (const float4*)cur;
        int n4 = D >> 2;
        float sum = 0.0f;
        for (int k = lane; k < n4; k += 64) {
            float4 a = rp[k];
            float4 b = c4[k];
            sum = fmaf(a.x, b.x, sum);
            sum = fmaf(a.y, b.y, sum);
            sum = fmaf(a.z, b.z, sum);
            sum = fmaf(a.w, b.w, sum);
        }
        sum = wave_sum(sum);
        if (lane == 0) {
            float sc = sum * scale;
            float w = weights[row] * expf(-LAMBDA_DECAY * fabsf(t_new[0] - ts[row]));
            e = expf(sc);
            pw = e * w;
            p[row] = pw;
        }
    }
    if (lane == 0) { shE[wid] = e; shS[wid] = pw; }
    __syncthreads();
    if (threadIdx.x == 0) {
        partE[blockIdx.x] = shE[0] + shE[1] + shE[2] + shE[3];
        partS[blockIdx.x] = shS[0] + shS[1] + shS[2] + shS[3];
    }
}

// K2: reduce 2048-element partials -> inv = 1/(S + 1e-9 E); zero acc.
__global__ __launch_bounds__(1024) void reduce_kernel(
    const float* __restrict__ partE, const float* __restrict__ partS, int n,
    float* __restrict__ invOut, float* __restrict__ acc, int D)
{
    __shared__ float sh[16];
    float E = 0.0f, S = 0.0f;
    for (int i = threadIdx.x; i < n; i += 1024) { E += partE[i]; S += partS[i]; }
    E = block_sum<16, 1024>(E, sh);
    S = block_sum<16, 1024>(S, sh);
    if (threadIdx.x == 0) invOut[0] = 1.0f / (S + 1e-9f * E);
    for (int d = threadIdx.x; d < D; d += 1024) acc[d] = 0.0f;
}

// K3: acc[d] += sum_{r in chunk} p[r] * states[r][d]  (inv folded into K4).
// grid = (D/1024, M/rowsPerBlock), block = 256, float4 per thread.
__global__ __launch_bounds__(256) void wsum_kernel(
    const float* __restrict__ states, const float* __restrict__ p,
    float* __restrict__ acc, int M, int D, int rowsPerBlock)
{
    int c = blockIdx.x * (256 * 4) + threadIdx.x * 4;
    int r0 = blockIdx.y * rowsPerBlock;
    int r1 = r0 + rowsPerBlock;
    if (r1 > M) r1 = M;
    float4 a = make_float4(0.0f, 0.0f, 0.0f, 0.0f);
    for (int r = r0; r < r1; ++r) {
        float cf = p[r];
        const float4 s = *(const float4*)(states + (size_t)r * D + c);
        a.x = fmaf(cf, s.x, a.x);
        a.y = fmaf(cf, s.y, a.y);
        a.z = fmaf(cf, s.z, a.z);
        a.w = fmaf(cf, s.w, a.w);
    }
    atomicAdd(&acc[c + 0], a.x);
    atomicAdd(&acc[c + 1], a.y);
    atomicAdd(&acc[c + 2], a.z);
    atomicAdd(&acc[c + 3], a.w);
}

// K4: attention_out = acc*inv; new = alpha*cur + (1-alpha)*attention_out;
// out = layernorm(new). Single block.
__global__ __launch_bounds__(1024) void finalize_kernel(
    const float* __restrict__ cur, const float* __restrict__ acc,
    const float* __restrict__ invIn, float* __restrict__ out, int D)
{
    __shared__ float sh[16];
    int tid = threadIdx.x;
    float inv = invIn[0];
    float s = 0.0f, s2 = 0.0f;
    for (int d = tid; d < D; d += 1024) {
        float v = ALPHA * cur[d] + (1.0f - ALPHA) * (acc[d] * inv);
        s += v;
        s2 += v * v;
    }
    s = block_sum<16, 1024>(s, sh);
    s2 = block_sum<16, 1024>(s2, sh);
    float mean = s / (float)D;
    float var = s2 / (float)D - mean * mean;
    float rstd = 1.0f / sqrtf(var + LN_EPS);
    for (int d = tid; d < D; d += 1024) {
        float v = ALPHA * cur[d] + (1.0f - ALPHA) * (acc[d] * inv);
        out[d] = (v - mean) * rstd;
    }
}

extern "C" void kernel_launch(void* const* d_in, const int* in_sizes, int n_in,
                              void* d_out, int out_size, void* d_ws, size_t ws_size,
                              hipStream_t stream) {
    const float* states       = (const float*)d_in[0];
    const float* weights      = (const float*)d_in[1];
    const float* timestamps   = (const float*)d_in[2];
    const float* current      = (const float*)d_in[3];
    // d_in[4] = sensed_state: not used in the output math.
    const float* t_new        = (const float*)d_in[5];
    float* out = (float*)d_out;

    const int M = in_sizes[1];               // 8192
    const int D = in_sizes[3];               // 4096

    const int nBlocksK1 = (M + 3) / 4;       // 2048

    float* ws    = (float*)d_ws;
    float* p     = ws;                        // [M]
    float* partE = ws + M;                    // [nBlocksK1]
    float* partS = partE + nBlocksK1;         // [nBlocksK1]
    float* inv   = partS + nBlocksK1;         // [1]
    float* acc   = inv + 1;                   // [D]

    const float scale = 1.0f / sqrtf((float)D);

    scores_kernel<<<nBlocksK1, 256, 0, stream>>>(
        states, current, weights, timestamps, t_new, p, partE, partS, M, D, scale);

    reduce_kernel<<<1, 1024, 0, stream>>>(partE, partS, nBlocksK1, inv, acc, D);

    {
        const int rowsPerBlock = 64;
        dim3 grid(D / 1024, (M + rowsPerBlock - 1) / rowsPerBlock);  // (4, 128)
        wsum_kernel<<<grid, 256, 0, stream>>>(states, p, acc, M, D, rowsPerBlock);
    }

    finalize_kernel<<<1, 1024, 0, stream>>>(current, acc, inv, out, D);
}

// Round 3
// 41.312 us; speedup vs baseline: 2.1356x; 1.6795x over previous
//
#include <hip/hip_runtime.h>
#include <math.h>

#define LAMBDA_DECAY 0.01f
#define ALPHA 0.95f
#define LN_EPS 1e-5f

// Problem geometry (reference: M=8192, D=4096).
#define WPB 4        // waves per block in K1 (256 threads)
#define RPW 4        // rows per wave in K1
#define NPART 512    // K1 blocks = M / (WPB*RPW)
#define G2 64        // partials reduced per K2 block
#define NP2 8        // NPART / G2 second-level partials

static __device__ __forceinline__ float wave_sum_all(float v) {
#pragma unroll
    for (int o = 32; o > 0; o >>= 1) v += __shfl_xor(v, o);
    return v;
}

// Block-wide sum broadcast. sh >= 16 floats.
static __device__ float block_sum(float v, float* sh, int nwaves) {
    int lane = threadIdx.x & 63;
    int w = threadIdx.x >> 6;
    v = wave_sum_all(v);
    if (lane == 0) sh[w] = v;
    __syncthreads();
    float r = 0.0f;
    for (int i = 0; i < nwaves; ++i) r += sh[i];
    __syncthreads();
    return r;
}

// K1: single pass over states. Wave-per-row, no barriers in the hot loop.
//   score = dot(row, cur)*scale ; p = exp(score) * weights*exp(-l*|tn-ts|)
//   acc[d] += p * row[d]  (full row per wave, in registers)
// Epilogue: combine 4 wave-accs via LDS, write one 4096-float partial per
// block + partial E (sum exp) and S (sum p).
__global__ __launch_bounds__(256, 2) void fused_kernel(
    const float* __restrict__ states, const float* __restrict__ cur,
    const float* __restrict__ weights, const float* __restrict__ ts,
    const float* __restrict__ t_new,
    float* __restrict__ partial, float* __restrict__ partE, float* __restrict__ partS,
    int M, int D, float scale)
{
    __shared__ float4 lds4[1024];          // 16 KB: block column accumulator
    __shared__ float shE[WPB], shS[WPB];

    const int wid = threadIdx.x >> 6;
    const int lane = threadIdx.x & 63;
    const int r0 = (blockIdx.x * WPB + wid) * RPW;

    const float4* c4 = (const float4*)cur;
    float4 curv[16];
#pragma unroll
    for (int j = 0; j < 16; ++j) curv[j] = c4[j * 64 + lane];

    float4 acc[16];
#pragma unroll
    for (int j = 0; j < 16; ++j) acc[j] = make_float4(0.f, 0.f, 0.f, 0.f);

    float E = 0.0f, S = 0.0f;
    const float tn = t_new[0];

    for (int rr = 0; rr < RPW; ++rr) {
        const int row = r0 + rr;
        if (row >= M) break;
        const float4* rp = (const float4*)(states + (size_t)row * D);
        float4 rv[16];
#pragma unroll
        for (int j = 0; j < 16; ++j) rv[j] = rp[j * 64 + lane];

        float s = 0.0f;
#pragma unroll
        for (int j = 0; j < 16; ++j) {
            s = fmaf(rv[j].x, curv[j].x, s);
            s = fmaf(rv[j].y, curv[j].y, s);
            s = fmaf(rv[j].z, curv[j].z, s);
            s = fmaf(rv[j].w, curv[j].w, s);
        }
        s = wave_sum_all(s);                       // all lanes hold the dot

        const float e = expf(s * scale);
        const float w = weights[row] * expf(-LAMBDA_DECAY * fabsf(tn - ts[row]));
        const float p = e * w;
        E += e; S += p;

#pragma unroll
        for (int j = 0; j < 16; ++j) {
            acc[j].x = fmaf(p, rv[j].x, acc[j].x);
            acc[j].y = fmaf(p, rv[j].y, acc[j].y);
            acc[j].z = fmaf(p, rv[j].z, acc[j].z);
            acc[j].w = fmaf(p, rv[j].w, acc[j].w);
        }
    }

    // Combine the 4 wave accumulators in LDS (serial rounds, epilogue-only).
    if (wid == 0) {
#pragma unroll
        for (int j = 0; j < 16; ++j) lds4[j * 64 + lane] = acc[j];
        if (lane == 0) { shE[0] = E; shS[0] = S; }
    }
    __syncthreads();
    for (int w = 1; w < WPB; ++w) {
        if (wid == w) {
#pragma unroll
            for (int j = 0; j < 16; ++j) {
                float4 t = lds4[j * 64 + lane];
                t.x += acc[j].x; t.y += acc[j].y; t.z += acc[j].z; t.w += acc[j].w;
                lds4[j * 64 + lane] = t;
            }
            if (lane == 0) { shE[w] = E; shS[w] = S; }
        }
        __syncthreads();
    }

    float4* pb = (float4*)(partial + (size_t)blockIdx.x * D);
#pragma unroll
    for (int jj = 0; jj < 4; ++jj)
        pb[jj * 256 + threadIdx.x] = lds4[jj * 256 + threadIdx.x];
    if (threadIdx.x == 0) {
        float e = 0.f, sp = 0.f;
        for (int w = 0; w < WPB; ++w) { e += shE[w]; sp += shS[w]; }
        partE[blockIdx.x] = e;
        partS[blockIdx.x] = sp;
    }
}

// K2: tree-reduce partials: 512 -> 8 per column.
// grid = (D/256, NP2); block handles 256 columns over G2 partials.
__global__ __launch_bounds__(256) void reduce_kernel(
    const float* __restrict__ partial, float* __restrict__ partial2, int D)
{
    const int col = blockIdx.x * 256 + threadIdx.x;
    const int b0 = blockIdx.y * G2;
    float a = 0.0f;
    for (int b = 0; b < G2; ++b)
        a += partial[(size_t)(b0 + b) * D + col];
    partial2[(size_t)blockIdx.y * D + col] = a;
}

// K3: final 8-way column sum + E/S reduce -> inv; blend; LayerNorm. 1 block.
__global__ __launch_bounds__(1024) void finalize_kernel(
    const float* __restrict__ partial2, const float* __restrict__ partE,
    const float* __restrict__ partS, const float* __restrict__ cur,
    float* __restrict__ out, int D)
{
    __shared__ float sh[16];
    const int tid = threadIdx.x;

    float E = 0.0f, S = 0.0f;
    for (int i = tid; i < NPART; i += 1024) { E += partE[i]; S += partS[i]; }
    E = block_sum(E, sh, 16);
    S = block_sum(S, sh, 16);
    const float inv = 1.0f / (S + 1e-9f * E);

    float v[4];
    float s = 0.0f, s2 = 0.0f;
#pragma unroll
    for (int k = 0; k < 4; ++k) {
        const int c = tid + k * 1024;
        float a = 0.0f;
#pragma unroll
        for (int y = 0; y < NP2; ++y) a += partial2[y * D + c];
        const float nv = ALPHA * cur[c] + (1.0f - ALPHA) * (a * inv);
        v[k] = nv;
        s += nv; s2 += nv * nv;
    }
    s = block_sum(s, sh, 16);
    s2 = block_sum(s2, sh, 16);
    const float mean = s / (float)D;
    const float var = s2 / (float)D - mean * mean;
    const float rstd = 1.0f / sqrtf(var + LN_EPS);
#pragma unroll
    for (int k = 0; k < 4; ++k)
        out[tid + k * 1024] = (v[k] - mean) * rstd;
}

extern "C" void kernel_launch(void* const* d_in, const int* in_sizes, int n_in,
                              void* d_out, int out_size, void* d_ws, size_t ws_size,
                              hipStream_t stream) {
    const float* states     = (const float*)d_in[0];
    const float* weights    = (const float*)d_in[1];
    const float* timestamps = (const float*)d_in[2];
    const float* current    = (const float*)d_in[3];
    // d_in[4] = sensed_state: not used in the output math.
    const float* t_new      = (const float*)d_in[5];
    float* out = (float*)d_out;

    const int M = in_sizes[1];   // 8192
    const int D = in_sizes[3];   // 4096

    float* ws       = (float*)d_ws;
    float* partial  = ws;                              // [NPART * D]  (8 MiB)
    float* partial2 = partial + (size_t)NPART * D;     // [NP2 * D]
    float* partE    = partial2 + (size_t)NP2 * D;      // [NPART]
    float* partS    = partE + NPART;                   // [NPART]

    const float scale = 1.0f / sqrtf((float)D);

    fused_kernel<<<NPART, 256, 0, stream>>>(
        states, current, weights, timestamps, t_new,
        partial, partE, partS, M, D, scale);

    {
        dim3 grid(D / 256, NP2);   // (16, 8)
        reduce_kernel<<<grid, 256, 0, stream>>>(partial, partial2, D);
    }

    finalize_kernel<<<1, 1024, 0, stream>>>(partial2, partE, partS, current, out, D);
}